// Round 3
// baseline (244.323 us; speedup 1.0000x reference)
//
#include <hip/hip_runtime.h>
#include <math.h>

typedef __bf16 bf16_t;
typedef __bf16 bf16x8 __attribute__((ext_vector_type(8)));
typedef __bf16 bf16x4v __attribute__((ext_vector_type(4)));
typedef float f32x4 __attribute__((ext_vector_type(4)));
typedef float f32x16 __attribute__((ext_vector_type(16)));

#define LOG2E 1.4426950408889634f
#define MBIAS_C (-1e12f * LOG2E)

#if __has_builtin(__builtin_amdgcn_exp2f)
#define EXP2F(x) __builtin_amdgcn_exp2f(x)
#else
#define EXP2F(x) exp2f(x)
#endif

typedef __attribute__((address_space(1))) const unsigned int g_u32;
typedef __attribute__((address_space(3))) unsigned int l_u32;
__device__ __forceinline__ void load_lds_16B(const void* g, void* l){
  __builtin_amdgcn_global_load_lds((g_u32*)g, (l_u32*)l, 16, 0, 0);
}

__device__ __forceinline__ f32x16 zero16(){
  f32x16 z;
  #pragma unroll
  for (int i = 0; i < 16; i++) z[i] = 0.f;
  return z;
}

typedef union { bf16x4v b4; uint2 u2; } pk8;
typedef union { uint2 h[2]; bf16x8 b8; } pk16;
typedef union { float4 f4[4]; f32x16 v; } cinit_t;

// ---------------- cast q,k,v fp32 -> bf16 planes ----------------
__global__ __launch_bounds__(256) void cast3_kernel(const float* __restrict__ q,
                                                    const float* __restrict__ k,
                                                    const float* __restrict__ v,
                                                    bf16_t* __restrict__ out){
  int z = blockIdx.y;
  const float* x = (z == 0) ? q : (z == 1) ? k : v;
  int i = blockIdx.x * 256 + threadIdx.x;
  float4 f = reinterpret_cast<const float4*>(x)[i];
  bf16x4v w;
  w[0] = (bf16_t)f.x; w[1] = (bf16_t)f.y; w[2] = (bf16_t)f.z; w[3] = (bf16_t)f.w;
  reinterpret_cast<bf16x4v*>(out + (size_t)z * 4194304)[i] = w;
}

// ---------------- mask prescale: ms[i] = bf16(mask[i] * (-1e12 * log2e)) ----------------
// bf16 is safe: mask==0 -> exact 0; mask!=0 -> exp2(-1.6e12*(1+/-0.4%)) == 0 either way.
__global__ __launch_bounds__(256) void mask_scale_kernel(const float* __restrict__ mask,
                                                         bf16_t* __restrict__ ms){
  int i = blockIdx.x * 256 + threadIdx.x;
  ms[i] = (bf16_t)(mask[i] * MBIAS_C);
}

// ---------------- weight transpose+cast ----------------
__global__ __launch_bounds__(256) void wtrans4_kernel(const float* __restrict__ Wq,
                                                      const float* __restrict__ Wk,
                                                      const float* __restrict__ Wv,
                                                      const float* __restrict__ Wo,
                                                      bf16_t* __restrict__ Wcat,
                                                      bf16_t* __restrict__ Wot){
  __shared__ float T[32][33];
  int z = blockIdx.z;
  const float* W = (z == 0) ? Wq : (z == 1) ? Wk : (z == 2) ? Wv : Wo;
  bf16_t* dst = (z < 3) ? (Wcat + (size_t)z * 1024 * 1024) : Wot;
  int x = threadIdx.x, y = threadIdx.y;
  int k0 = blockIdx.y * 32, n0 = blockIdx.x * 32;
  #pragma unroll
  for (int i = 0; i < 4; i++) T[y + 8*i][x] = W[(size_t)(k0 + y + 8*i) * 1024 + n0 + x];
  __syncthreads();
  #pragma unroll
  for (int i = 0; i < 4; i++) dst[(size_t)(n0 + y + 8*i) * 1024 + k0 + x] = (bf16_t)T[x][y + 8*i];
}

// ---------------- shared epilogue for QKV GEMMs: write q/k/v planes ----------------
__device__ __forceinline__ void qkv_epilogue(f32x4 (&acc)[4][4], int seg, int n0g, int m0,
                                             int wm, int wn, int l16, int lq,
                                             const float* bias, bf16_t* qp, bf16_t* kp,
                                             bf16_t* vh){
  bf16_t* Cp = (seg == 0) ? qp : (seg == 1) ? kp : vh;
  float scale = (seg == 0) ? 0.125f * LOG2E : 1.0f;  // fold softmax scale + log2e into Q
  #pragma unroll
  for (int ti = 0; ti < 4; ti++){
    #pragma unroll
    for (int tj = 0; tj < 4; tj++){
      int col = (n0g + wn + tj*16 + l16) & 1023;
      float bvv = bias[col];
      #pragma unroll
      for (int r = 0; r < 4; r++){
        int row = m0 + wm + ti*16 + lq*4 + r;
        Cp[(size_t)row * 1024 + col] = (bf16_t)((acc[ti][tj][r] + bvv) * scale);
      }
    }
  }
}

// ---------------- fused QKV GEMM, all-bf16 (path A), counted-vmcnt double-buffer ----------------
__global__ __launch_bounds__(256) void gemm_qkv_bf(const bf16_t* __restrict__ qkvin,
                                                   const bf16_t* __restrict__ Wcat,
                                                   const float* __restrict__ bq,
                                                   const float* __restrict__ bk,
                                                   const float* __restrict__ bv,
                                                   bf16_t* __restrict__ qp,
                                                   bf16_t* __restrict__ kp,
                                                   bf16_t* __restrict__ vh){
  const int K = 1024;
  __shared__ __align__(16) bf16_t As[2][128*32];
  __shared__ __align__(16) bf16_t Bs[2][128*32];
  int tid = threadIdx.x, wave = tid >> 6, lane = tid & 63;
  int l16 = lane & 15, lq = lane >> 4;
  int n0g = blockIdx.x * 128;
  int seg = n0g >> 10;
  const bf16_t* A   = qkvin + (size_t)seg * 4194304;
  const float* bias = (seg == 0) ? bq : (seg == 1) ? bk : bv;
  int m0 = blockIdx.y * 128;
  int wm = (wave >> 1) * 64, wn = (wave & 1) * 64;
  int cposR = lq ^ ((l16 >> 2) & 3);
  f32x4 acc[4][4] = {};

  auto stage = [&](int kt, int bsel){
    #pragma unroll
    for (int i = 0; i < 2; i++){
      int u = tid + 256*i;
      int r = u >> 2, cpos = u & 3, cg = cpos ^ ((r >> 2) & 3);
      int ldsoff = (wave*64 + 256*i) * 16;
      load_lds_16B(&A[(size_t)(m0 + r) * K + kt + cg*8], (char*)As[bsel] + ldsoff);
      load_lds_16B(&Wcat[(size_t)(n0g + r) * K + kt + cg*8], (char*)Bs[bsel] + ldsoff);
    }
  };
  auto compute = [&](int cur){
    bf16x8 af[4], bfr[4];
    #pragma unroll
    for (int t = 0; t < 4; t++) af[t]  = *reinterpret_cast<bf16x8*>(&As[cur][(wm + t*16 + l16)*32 + cposR*8]);
    #pragma unroll
    for (int t = 0; t < 4; t++) bfr[t] = *reinterpret_cast<bf16x8*>(&Bs[cur][(wn + t*16 + l16)*32 + cposR*8]);
    #pragma unroll
    for (int ti = 0; ti < 4; ti++)
      #pragma unroll
      for (int tj = 0; tj < 4; tj++)
        acc[ti][tj] = __builtin_amdgcn_mfma_f32_16x16x32_bf16(af[ti], bfr[tj], acc[ti][tj], 0, 0, 0);
  };

  stage(0, 0);
  #pragma unroll 1
  for (int it = 0; it < 31; ++it){
    stage((it + 1) * 32, (it + 1) & 1);
    asm volatile("s_waitcnt vmcnt(4)" ::: "memory");
    __builtin_amdgcn_sched_barrier(0);
    __builtin_amdgcn_s_barrier();
    __builtin_amdgcn_sched_barrier(0);
    compute(it & 1);
    __builtin_amdgcn_sched_barrier(0);
    __builtin_amdgcn_s_barrier();
    __builtin_amdgcn_sched_barrier(0);
  }
  asm volatile("s_waitcnt vmcnt(0)" ::: "memory");
  __builtin_amdgcn_sched_barrier(0);
  __builtin_amdgcn_s_barrier();
  __builtin_amdgcn_sched_barrier(0);
  compute(1);

  qkv_epilogue(acc, seg, n0g, m0, wm, wn, l16, lq, bias, qp, kp, vh);
}

// ---------------- fused QKV GEMM, fp32-A fused-cvt (path B fallback) ----------------
__global__ __launch_bounds__(256) void gemm_qkv_f32(const float* __restrict__ qi,
                                                    const float* __restrict__ ki,
                                                    const float* __restrict__ vi,
                                                    const bf16_t* __restrict__ Wcat,
                                                    const float* __restrict__ bq,
                                                    const float* __restrict__ bk,
                                                    const float* __restrict__ bv,
                                                    bf16_t* __restrict__ qp,
                                                    bf16_t* __restrict__ kp,
                                                    bf16_t* __restrict__ vh){
  const int K = 1024;
  __shared__ __align__(16) float  Asf[128*32];
  __shared__ __align__(16) bf16_t Bs[128*32];
  int tid = threadIdx.x, wave = tid >> 6, lane = tid & 63;
  int l16 = lane & 15, lq = lane >> 4;
  int n0g = blockIdx.x * 128;
  int seg = n0g >> 10;
  const float* A    = (seg == 0) ? qi : (seg == 1) ? ki : vi;
  const float* bias = (seg == 0) ? bq : (seg == 1) ? bk : bv;
  int m0 = blockIdx.y * 128;
  int wm = (wave >> 1) * 64, wn = (wave & 1) * 64;
  int cposR = lq ^ ((l16 >> 2) & 3);
  int ca0 = (2*lq)     ^ (l16 & 7);
  int ca1 = (2*lq + 1) ^ (l16 & 7);
  f32x4 acc[4][4] = {};
  for (int kt = 0; kt < K; kt += 32){
    __syncthreads();
    #pragma unroll
    for (int i = 0; i < 4; i++){
      int u = tid + 256*i;
      int r = u >> 3, cpos = u & 7, cg = cpos ^ (r & 7);
      load_lds_16B(&A[(size_t)(m0 + r) * K + kt + cg*4], (char*)Asf + (wave*64 + 256*i)*16);
    }
    #pragma unroll
    for (int i = 0; i < 2; i++){
      int u = tid + 256*i;
      int r = u >> 2, cpos = u & 3, cg = cpos ^ ((r >> 2) & 3);
      load_lds_16B(&Wcat[(size_t)(n0g + r) * K + kt + cg*8], (char*)Bs + (wave*64 + 256*i)*16);
    }
    __syncthreads();
    bf16x8 af[4], bfr[4];
    #pragma unroll
    for (int t = 0; t < 4; t++){
      int row = wm + t*16 + l16;
      f32x4 x0 = *reinterpret_cast<f32x4*>(&Asf[row*32 + ca0*4]);
      f32x4 x1 = *reinterpret_cast<f32x4*>(&Asf[row*32 + ca1*4]);
      bf16x8 a;
      a[0] = (bf16_t)x0[0]; a[1] = (bf16_t)x0[1]; a[2] = (bf16_t)x0[2]; a[3] = (bf16_t)x0[3];
      a[4] = (bf16_t)x1[0]; a[5] = (bf16_t)x1[1]; a[6] = (bf16_t)x1[2]; a[7] = (bf16_t)x1[3];
      af[t] = a;
    }
    #pragma unroll
    for (int t = 0; t < 4; t++) bfr[t] = *reinterpret_cast<bf16x8*>(&Bs[(wn + t*16 + l16)*32 + cposR*8]);
    #pragma unroll
    for (int ti = 0; ti < 4; ti++)
      #pragma unroll
      for (int tj = 0; tj < 4; tj++)
        acc[ti][tj] = __builtin_amdgcn_mfma_f32_16x16x32_bf16(af[ti], bfr[tj], acc[ti][tj], 0, 0, 0);
  }
  qkv_epilogue(acc, seg, n0g, m0, wm, wn, l16, lq, bias, qp, kp, vh);
}

// ---------------- output GEMM: d_out = ctx @ Wot^T + bo, counted-vmcnt double-buffer ----------------
__global__ __launch_bounds__(256) void gemm_out(const bf16_t* __restrict__ A,
                                                const bf16_t* __restrict__ Bt,
                                                const float* __restrict__ bias,
                                                float* __restrict__ C){
  const int K = 1024, N = 1024;
  __shared__ __align__(16) bf16_t As[2][128*64];
  __shared__ __align__(16) bf16_t Bs[2][64*64];
  int tid = threadIdx.x, wave = tid >> 6, lane = tid & 63;
  int l16 = lane & 15, lq = lane >> 4;
  int m0 = blockIdx.y * 128, n0 = blockIdx.x * 64;
  int wm = wave * 32;
  f32x4 acc[2][4] = {};

  auto stage = [&](int kt, int bsel){
    #pragma unroll
    for (int i = 0; i < 4; i++){
      int u = tid + 256*i;
      int r = u >> 3, cpos = u & 7, cg = cpos ^ (r & 7);
      load_lds_16B(&A[(size_t)(m0 + r) * K + kt + cg*8], (char*)As[bsel] + (wave*64 + 256*i)*16);
    }
    #pragma unroll
    for (int i = 0; i < 2; i++){
      int u = tid + 256*i;
      int r = u >> 3, cpos = u & 7, cg = cpos ^ (r & 7);
      load_lds_16B(&Bt[(size_t)(n0 + r) * K + kt + cg*8], (char*)Bs[bsel] + (wave*64 + 256*i)*16);
    }
  };
  auto compute = [&](int cur){
    #pragma unroll
    for (int kk = 0; kk < 2; kk++){
      bf16x8 af[2], bfr[4];
      #pragma unroll
      for (int t = 0; t < 2; t++){
        int row = wm + t*16 + l16, cpos = (kk*4 + lq) ^ (l16 & 7);
        af[t] = *reinterpret_cast<bf16x8*>(&As[cur][row*64 + cpos*8]);
      }
      #pragma unroll
      for (int t = 0; t < 4; t++){
        int row = t*16 + l16, cpos = (kk*4 + lq) ^ (l16 & 7);
        bfr[t] = *reinterpret_cast<bf16x8*>(&Bs[cur][row*64 + cpos*8]);
      }
      #pragma unroll
      for (int ti = 0; ti < 2; ti++)
        #pragma unroll
        for (int tj = 0; tj < 4; tj++)
          acc[ti][tj] = __builtin_amdgcn_mfma_f32_16x16x32_bf16(af[ti], bfr[tj], acc[ti][tj], 0, 0, 0);
    }
  };

  stage(0, 0);
  #pragma unroll 1
  for (int it = 0; it < 15; ++it){
    stage((it + 1) * 64, (it + 1) & 1);
    asm volatile("s_waitcnt vmcnt(6)" ::: "memory");
    __builtin_amdgcn_sched_barrier(0);
    __builtin_amdgcn_s_barrier();
    __builtin_amdgcn_sched_barrier(0);
    compute(it & 1);
    __builtin_amdgcn_sched_barrier(0);
    __builtin_amdgcn_s_barrier();
    __builtin_amdgcn_sched_barrier(0);
  }
  asm volatile("s_waitcnt vmcnt(0)" ::: "memory");
  __builtin_amdgcn_sched_barrier(0);
  __builtin_amdgcn_s_barrier();
  __builtin_amdgcn_sched_barrier(0);
  compute(1);

  #pragma unroll
  for (int ti = 0; ti < 2; ti++){
    #pragma unroll
    for (int tj = 0; tj < 4; tj++){
      int col = n0 + tj*16 + l16;
      float bvv = bias[col];
      #pragma unroll
      for (int r = 0; r < 4; r++){
        int row = m0 + wm + ti*16 + lq*4 + r;
        C[(size_t)row * N + col] = acc[ti][tj][r] + bvv;
      }
    }
  }
}

// ---------------- per-head V transpose: vh[b*2048+s][h*64+d] -> Vt[(b*16+h)*64+d][s] ----------------
__global__ __launch_bounds__(256) void vtrans_kernel(const bf16_t* __restrict__ vh,
                                                     bf16_t* __restrict__ Vt){
  __shared__ bf16_t T[64][72];
  int tid = threadIdx.x;
  int s0 = blockIdx.x * 64, h = blockIdx.y, b = blockIdx.z;
  #pragma unroll
  for (int i = 0; i < 2; i++){
    int u = tid + 256*i;
    int r = u >> 3, c = (u & 7) * 8;
    *reinterpret_cast<uint4*>(&T[r][c]) =
      *reinterpret_cast<const uint4*>(&vh[(size_t)(b*2048 + s0 + r) * 1024 + h*64 + c]);
  }
  __syncthreads();
  #pragma unroll
  for (int i = 0; i < 2; i++){
    int u = tid + 256*i;
    int d = u >> 3, cs = (u & 7) * 8;
    bf16_t t8[8];
    #pragma unroll
    for (int j = 0; j < 8; j++) t8[j] = T[cs + j][d];
    *reinterpret_cast<uint4*>(&Vt[(size_t)((b*16 + h)*64 + d) * 2048 + s0 + cs]) =
      *reinterpret_cast<uint4*>(t8);
  }
}

// ---------------- flash attention v6b: counted-vmcnt pipeline (no barrier drains) ----------------
// Block: 64 q-rows, 4 waves = (qhalf, khalf). Per tile:
//   stage(t+1) -> s_waitcnt vmcnt(4) (t's 4 loads retired; t+1's stay in flight)
//   -> s_barrier -> compute(t) -> s_barrier.  No vmcnt(0) drain in the main loop.
// Mask: prescaled bf16 row staged to LDS once (lgkm-only reads keep vmcnt count exact);
// unpacked by u16<<16 into the first QK MFMA's C operand.
// P-transpose: __shfl_xor(…,32) (harness-verified v5 form; permlane32_swap direction
// was wrong on HW — round-2 post-mortem). Row-sum: scalar lacc + v4 epilogue.
// LDS 37.4 KB -> 4 blocks/CU; __launch_bounds__(256,4) caps VGPR at 128.
__global__ __launch_bounds__(256, 4) void attn_kernel(const bf16_t* __restrict__ qp,
                                                      const bf16_t* __restrict__ kp,
                                                      const bf16_t* __restrict__ vt,
                                                      const bf16_t* __restrict__ ms,
                                                      bf16_t* __restrict__ ctx){
  const int S = 2048, D = 1024, HD = 64;
  __shared__ __align__(16) char smem[37376];
  // K bufs [0,16384), V bufs [16384,32768), mask bf16 [32768,36864),
  // Lsum [36864,37120), Lcomb [37120,37376). Opart overlays [0,16384) in epilogue.
  float* Lsum  = (float*)(smem + 36864);
  float* Lcomb = (float*)(smem + 37120);
  float* Opart = (float*)smem;
  int tid = threadIdx.x, wave = tid >> 6, lane = tid & 63;
  int l32 = lane & 31, H = lane >> 5;
  int qhalf = wave & 1, khalf = wave >> 1;
  int qt = blockIdx.x, h = blockIdx.y, b = blockIdx.z;
  const bf16_t* Qg  = qp + (size_t)b*S*D + h*HD;
  const bf16_t* Kg  = kp + (size_t)b*S*D + h*HD;
  const bf16_t* Vg  = vt + (size_t)(b*16 + h)*HD*S;
  const bf16_t* Mg2 = ms + (size_t)b*S;

  auto stage = [&](int kt, int bsel){
    char* Kd = smem + bsel*8192;
    char* Vd = smem + 16384 + bsel*8192;
    #pragma unroll
    for (int i = 0; i < 2; i++){
      int u = tid + 256*i;
      int r = u >> 3, c = u & 7, cg = c ^ (r & 7);
      int ldsoff = (wave*64 + 256*i) * 16;  // wave-uniform base; HW adds lane*16
      load_lds_16B(&Kg[(size_t)(kt + r) * D + cg*8], Kd + ldsoff);
      load_lds_16B(&Vg[(size_t)r * S + kt + cg*8], Vd + ldsoff);
    }
  };

  // Q fragments straight from global: B-operand, lane n=qrow, k=d=16s+8H+j
  int qrow = qt*64 + qhalf*32 + l32;
  bf16x8 qf[4];
  #pragma unroll
  for (int s = 0; s < 4; s++)
    qf[s] = *reinterpret_cast<const bf16x8*>(&Qg[(size_t)qrow * D + s*16 + 8*H]);

  f32x16 o0 = zero16(), o1 = zero16();
  float lacc = 0.f;
  int krow = khalf*32 + l32;
  // this wave's mask sub-row base (bf16): element (khalf*32 + 4H), uint2 = 4 bf16
  const uint2* mrow = reinterpret_cast<const uint2*>(smem + 32768 + (size_t)(khalf*32 + 4*H)*2);

  // prologue: mask row (1 load/thread) + tile 0 (4 loads/thread)
  load_lds_16B(&Mg2[(size_t)tid*8], smem + 32768 + wave*1024);
  stage(0, 0);

  auto tile_compute = [&](int kt, int cur){
    bf16_t* Ks  = (bf16_t*)(smem + cur*8192);
    bf16_t* Vts = (bf16_t*)(smem + 16384 + cur*8192);
    // mask C-init from LDS bf16: key = kt + khalf*32 + 8g + 4H + r
    cinit_t ci;
    #pragma unroll
    for (int g = 0; g < 4; g++){
      uint2 mu = mrow[(kt >> 2) + 2*g];
      ci.f4[g].x = __uint_as_float(mu.x << 16);
      ci.f4[g].y = __uint_as_float(mu.x & 0xFFFF0000u);
      ci.f4[g].z = __uint_as_float(mu.y << 16);
      ci.f4[g].w = __uint_as_float(mu.y & 0xFFFF0000u);
    }
    // QK: one 32x32 Sc^T tile, chained over d=64, mask rides in as C operand
    f32x16 sc;
    #pragma unroll
    for (int s = 0; s < 4; s++){
      int cp = (2*s + H) ^ (l32 & 7);  // krow&7 == l32&7
      bf16x8 kf = *reinterpret_cast<bf16x8*>(&Ks[krow*64 + cp*8]);
      if (s == 0) sc = __builtin_amdgcn_mfma_f32_32x32x16_bf16(kf, qf[0], ci.v, 0, 0, 0);
      else        sc = __builtin_amdgcn_mfma_f32_32x32x16_bf16(kf, qf[s], sc, 0, 0, 0);
    }
    // exp; C-layout: lane owns q-col l32; tile-key = khalf*32 + 8g + 4H + r (reg=4g+r)
    pk8 grp[4];
    #pragma unroll
    for (int g = 0; g < 4; g++){
      float p0 = EXP2F(sc[4*g+0]);
      float p1 = EXP2F(sc[4*g+1]);
      float p2 = EXP2F(sc[4*g+2]);
      float p3 = EXP2F(sc[4*g+3]);
      lacc += (p0 + p1) + (p2 + p3);
      pk8 w;
      w.b4[0] = (bf16_t)p0; w.b4[1] = (bf16_t)p1; w.b4[2] = (bf16_t)p2; w.b4[3] = (bf16_t)p3;
      grp[g] = w;
    }
    // PV with register transpose (verified shfl_xor form); window kk covers
    // tile-keys khalf*32 + 16kk + 8H + j
    #pragma unroll
    for (int kk = 0; kk < 2; kk++){
      uint2 ga = grp[2*kk].u2;
      uint2 gb = grp[2*kk+1].u2;
      uint2 send = H ? ga : gb;
      uint2 recv;
      recv.x = (unsigned)__shfl_xor((int)send.x, 32);
      recv.y = (unsigned)__shfl_xor((int)send.y, 32);
      pk16 fr;
      fr.h[0] = H ? recv : ga;
      fr.h[1] = H ? gb : recv;
      int cp = (4*khalf + 2*kk + H) ^ (l32 & 7);
      bf16x8 vf0 = *reinterpret_cast<bf16x8*>(&Vts[l32*64 + cp*8]);
      bf16x8 vf1 = *reinterpret_cast<bf16x8*>(&Vts[(32 + l32)*64 + cp*8]);
      o0 = __builtin_amdgcn_mfma_f32_32x32x16_bf16(fr.b8, vf0, o0, 0, 0, 0);
      o1 = __builtin_amdgcn_mfma_f32_32x32x16_bf16(fr.b8, vf1, o1, 0, 0, 0);
    }
  };

  #pragma unroll 1
  for (int it = 0; it < 31; ++it){
    stage((it + 1) * 64, (it + 1) & 1);
    asm volatile("s_waitcnt vmcnt(4)" ::: "memory");
    __builtin_amdgcn_sched_barrier(0);
    __builtin_amdgcn_s_barrier();
    __builtin_amdgcn_sched_barrier(0);
    tile_compute(it * 64, it & 1);
    __builtin_amdgcn_sched_barrier(0);
    __builtin_amdgcn_s_barrier();
    __builtin_amdgcn_sched_barrier(0);
  }
  asm volatile("s_waitcnt vmcnt(0)" ::: "memory");
  __builtin_amdgcn_sched_barrier(0);
  __builtin_amdgcn_s_barrier();
  __builtin_amdgcn_sched_barrier(0);
  tile_compute(1984, 1);

  // epilogue: combine k-halves through LDS (overlays K/V bufs), normalize, store
  float lfull = lacc + __shfl_xor(lacc, 32);
  __syncthreads();
  if (khalf == 1){
    #pragma unroll
    for (int reg = 0; reg < 16; reg++){
      Opart[qhalf*2048 + reg*64 + lane]        = o0[reg];
      Opart[qhalf*2048 + 1024 + reg*64 + lane] = o1[reg];
    }
    if (H == 0) Lsum[qhalf*32 + l32] = lfull;
  }
  __syncthreads();
  if (khalf == 0){
    #pragma unroll
    for (int reg = 0; reg < 16; reg++){
      o0[reg] += Opart[qhalf*2048 + reg*64 + lane];
      o1[reg] += Opart[qhalf*2048 + 1024 + reg*64 + lane];
    }
    lfull += Lsum[qhalf*32 + l32];
    Lcomb[qhalf*32 + l32] = lfull;  // same-wave DS ordering; no barrier needed
    #pragma unroll
    for (int g = 0; g < 4; g++){
      f32x4 lv = *reinterpret_cast<f32x4*>(&Lcomb[qhalf*32 + 8*g + 4*H]);
      #pragma unroll
      for (int r = 0; r < 4; r++){
        float inv = 1.f / lv[r];
        int grow = qt*64 + qhalf*32 + 8*g + 4*H + r;
        size_t base = (size_t)(b*S + grow) * D + h*HD;
        ctx[base + l32]      = (bf16_t)(o0[4*g + r] * inv);
        ctx[base + 32 + l32] = (bf16_t)(o1[4*g + r] * inv);
      }
    }
  }
}

extern "C" void kernel_launch(void* const* d_in, const int* in_sizes, int n_in,
                              void* d_out, int out_size, void* d_ws, size_t ws_size,
                              hipStream_t stream){
  const float* q    = (const float*)d_in[0];
  const float* k    = (const float*)d_in[1];
  const float* v    = (const float*)d_in[2];
  const float* mask = (const float*)d_in[3];
  const float* Wq   = (const float*)d_in[4];
  const float* bq   = (const float*)d_in[5];
  const float* Wk   = (const float*)d_in[6];
  const float* bk   = (const float*)d_in[7];
  const float* Wv   = (const float*)d_in[8];
  const float* bv   = (const float*)d_in[9];
  const float* Wo   = (const float*)d_in[10];
  const float* bo   = (const float*)d_in[11];

  char* ws = (char*)d_ws;
  bf16_t* qp    = (bf16_t*)(ws);               // [0, 8 MiB)
  bf16_t* kp    = (bf16_t*)(ws + 8388608);     // [8, 16)
  bf16_t* vh    = (bf16_t*)(ws + 16777216);    // [16, 24)
  bf16_t* Wcat  = (bf16_t*)(ws + 25165824);    // [24, 30)
  bf16_t* Wot   = (bf16_t*)(ws + 31457280);    // [30, 32)
  bf16_t* Vt    = (bf16_t*)(ws + 33554432);    // [32, 40)
  bf16_t* ctx   = (bf16_t*)(ws + 41943040);    // [40, 48)
  bf16_t* qkvin = (bf16_t*)(ws + 33554432);    // [32, 56) path A only; dead before Vt/ctx live
  bf16_t* msbuf = (bf16_t*)(ws + 16777216);    // 8 KB, overlays vh (dead after vtrans)

  wtrans4_kernel<<<dim3(32,32,4), dim3(32,8), 0, stream>>>(Wq, Wk, Wv, Wo, Wcat, Wot);
  if (ws_size >= 58720256){
    cast3_kernel<<<dim3(4096,3), 256, 0, stream>>>(q, k, v, qkvin);
    gemm_qkv_bf<<<dim3(24,32), 256, 0, stream>>>(qkvin, Wcat, bq, bk, bv, qp, kp, vh);
  } else {
    gemm_qkv_f32<<<dim3(24,32), 256, 0, stream>>>(q, k, v, Wcat, bq, bk, bv, qp, kp, vh);
  }
  vtrans_kernel<<<dim3(32,16,2), 256, 0, stream>>>(vh, Vt);
  mask_scale_kernel<<<dim3(16), 256, 0, stream>>>(mask, msbuf);
  attn_kernel<<<dim3(32,16,2), 256, 0, stream>>>(qp, kp, Vt, msbuf, ctx);
  gemm_out<<<dim3(16,32), 256, 0, stream>>>(ctx, Wot, bo, (float*)d_out);
}

// Round 4
// 235.305 us; speedup vs baseline: 1.0383x; 1.0383x over previous
//
#include <hip/hip_runtime.h>
#include <math.h>

typedef __bf16 bf16_t;
typedef __bf16 bf16x8 __attribute__((ext_vector_type(8)));
typedef __bf16 bf16x4v __attribute__((ext_vector_type(4)));
typedef float f32x4 __attribute__((ext_vector_type(4)));
typedef float f32x16 __attribute__((ext_vector_type(16)));

#define LOG2E 1.4426950408889634f
#define MBIAS_C (-1e12f * LOG2E)

#if __has_builtin(__builtin_amdgcn_exp2f)
#define EXP2F(x) __builtin_amdgcn_exp2f(x)
#else
#define EXP2F(x) exp2f(x)
#endif

typedef __attribute__((address_space(1))) const unsigned int g_u32;
typedef __attribute__((address_space(3))) unsigned int l_u32;
__device__ __forceinline__ void load_lds_16B(const void* g, void* l){
  __builtin_amdgcn_global_load_lds((g_u32*)g, (l_u32*)l, 16, 0, 0);
}

__device__ __forceinline__ f32x16 zero16(){
  f32x16 z;
  #pragma unroll
  for (int i = 0; i < 16; i++) z[i] = 0.f;
  return z;
}

typedef union { bf16x4v b4; uint2 u2; } pk8;
typedef union { uint2 h[2]; bf16x8 b8; } pk16;
typedef union { float4 f4[4]; f32x16 v; } cinit_t;

// ---------------- cast q,k,v fp32 -> bf16 planes ----------------
__global__ __launch_bounds__(256) void cast3_kernel(const float* __restrict__ q,
                                                    const float* __restrict__ k,
                                                    const float* __restrict__ v,
                                                    bf16_t* __restrict__ out){
  int z = blockIdx.y;
  const float* x = (z == 0) ? q : (z == 1) ? k : v;
  int i = blockIdx.x * 256 + threadIdx.x;
  float4 f = reinterpret_cast<const float4*>(x)[i];
  bf16x4v w;
  w[0] = (bf16_t)f.x; w[1] = (bf16_t)f.y; w[2] = (bf16_t)f.z; w[3] = (bf16_t)f.w;
  reinterpret_cast<bf16x4v*>(out + (size_t)z * 4194304)[i] = w;
}

// ---------------- mask prescale: ms[i] = mask[i] * (-1e12 * log2e) ----------------
__global__ __launch_bounds__(256) void mask_scale_kernel(const float* __restrict__ mask,
                                                         float* __restrict__ ms){
  int i = blockIdx.x * 256 + threadIdx.x;
  ms[i] = mask[i] * MBIAS_C;
}

// ---------------- weight transpose+cast ----------------
__global__ __launch_bounds__(256) void wtrans4_kernel(const float* __restrict__ Wq,
                                                      const float* __restrict__ Wk,
                                                      const float* __restrict__ Wv,
                                                      const float* __restrict__ Wo,
                                                      bf16_t* __restrict__ Wcat,
                                                      bf16_t* __restrict__ Wot){
  __shared__ float T[32][33];
  int z = blockIdx.z;
  const float* W = (z == 0) ? Wq : (z == 1) ? Wk : (z == 2) ? Wv : Wo;
  bf16_t* dst = (z < 3) ? (Wcat + (size_t)z * 1024 * 1024) : Wot;
  int x = threadIdx.x, y = threadIdx.y;
  int k0 = blockIdx.y * 32, n0 = blockIdx.x * 32;
  #pragma unroll
  for (int i = 0; i < 4; i++) T[y + 8*i][x] = W[(size_t)(k0 + y + 8*i) * 1024 + n0 + x];
  __syncthreads();
  #pragma unroll
  for (int i = 0; i < 4; i++) dst[(size_t)(n0 + y + 8*i) * 1024 + k0 + x] = (bf16_t)T[x][y + 8*i];
}

// ---------------- shared epilogue for QKV GEMMs: write q/k/v planes ----------------
__device__ __forceinline__ void qkv_epilogue(f32x4 (&acc)[4][4], int seg, int n0g, int m0,
                                             int wm, int wn, int l16, int lq,
                                             const float* bias, bf16_t* qp, bf16_t* kp,
                                             bf16_t* vh){
  bf16_t* Cp = (seg == 0) ? qp : (seg == 1) ? kp : vh;
  float scale = (seg == 0) ? 0.125f * LOG2E : 1.0f;  // fold softmax scale + log2e into Q
  #pragma unroll
  for (int ti = 0; ti < 4; ti++){
    #pragma unroll
    for (int tj = 0; tj < 4; tj++){
      int col = (n0g + wn + tj*16 + l16) & 1023;
      float bvv = bias[col];
      #pragma unroll
      for (int r = 0; r < 4; r++){
        int row = m0 + wm + ti*16 + lq*4 + r;
        Cp[(size_t)row * 1024 + col] = (bf16_t)((acc[ti][tj][r] + bvv) * scale);
      }
    }
  }
}

// ---------------- fused QKV GEMM, all-bf16 (path A) ----------------
__global__ __launch_bounds__(256) void gemm_qkv_bf(const bf16_t* __restrict__ qkvin,
                                                   const bf16_t* __restrict__ Wcat,
                                                   const float* __restrict__ bq,
                                                   const float* __restrict__ bk,
                                                   const float* __restrict__ bv,
                                                   bf16_t* __restrict__ qp,
                                                   bf16_t* __restrict__ kp,
                                                   bf16_t* __restrict__ vh){
  const int K = 1024;
  __shared__ __align__(16) bf16_t As[128*32];
  __shared__ __align__(16) bf16_t Bs[128*32];
  int tid = threadIdx.x, wave = tid >> 6, lane = tid & 63;
  int l16 = lane & 15, lq = lane >> 4;
  int n0g = blockIdx.x * 128;
  int seg = n0g >> 10;
  const bf16_t* A   = qkvin + (size_t)seg * 4194304;
  const float* bias = (seg == 0) ? bq : (seg == 1) ? bk : bv;
  int m0 = blockIdx.y * 128;
  int wm = (wave >> 1) * 64, wn = (wave & 1) * 64;
  int cposR = lq ^ ((l16 >> 2) & 3);
  f32x4 acc[4][4] = {};
  for (int kt = 0; kt < K; kt += 32){
    __syncthreads();
    #pragma unroll
    for (int i = 0; i < 2; i++){
      int u = tid + 256*i;
      int r = u >> 2, cpos = u & 3, cg = cpos ^ ((r >> 2) & 3);
      int ldsoff = (wave*64 + 256*i) * 16;
      load_lds_16B(&A[(size_t)(m0 + r) * K + kt + cg*8], (char*)As + ldsoff);
      load_lds_16B(&Wcat[(size_t)(n0g + r) * K + kt + cg*8], (char*)Bs + ldsoff);
    }
    __syncthreads();
    bf16x8 af[4], bfr[4];
    #pragma unroll
    for (int t = 0; t < 4; t++) af[t]  = *reinterpret_cast<bf16x8*>(&As[(wm + t*16 + l16)*32 + cposR*8]);
    #pragma unroll
    for (int t = 0; t < 4; t++) bfr[t] = *reinterpret_cast<bf16x8*>(&Bs[(wn + t*16 + l16)*32 + cposR*8]);
    #pragma unroll
    for (int ti = 0; ti < 4; ti++)
      #pragma unroll
      for (int tj = 0; tj < 4; tj++)
        acc[ti][tj] = __builtin_amdgcn_mfma_f32_16x16x32_bf16(af[ti], bfr[tj], acc[ti][tj], 0, 0, 0);
  }
  qkv_epilogue(acc, seg, n0g, m0, wm, wn, l16, lq, bias, qp, kp, vh);
}

// ---------------- fused QKV GEMM, fp32-A fused-cvt (path B fallback) ----------------
__global__ __launch_bounds__(256) void gemm_qkv_f32(const float* __restrict__ qi,
                                                    const float* __restrict__ ki,
                                                    const float* __restrict__ vi,
                                                    const bf16_t* __restrict__ Wcat,
                                                    const float* __restrict__ bq,
                                                    const float* __restrict__ bk,
                                                    const float* __restrict__ bv,
                                                    bf16_t* __restrict__ qp,
                                                    bf16_t* __restrict__ kp,
                                                    bf16_t* __restrict__ vh){
  const int K = 1024;
  __shared__ __align__(16) float  Asf[128*32];
  __shared__ __align__(16) bf16_t Bs[128*32];
  int tid = threadIdx.x, wave = tid >> 6, lane = tid & 63;
  int l16 = lane & 15, lq = lane >> 4;
  int n0g = blockIdx.x * 128;
  int seg = n0g >> 10;
  const float* A    = (seg == 0) ? qi : (seg == 1) ? ki : vi;
  const float* bias = (seg == 0) ? bq : (seg == 1) ? bk : bv;
  int m0 = blockIdx.y * 128;
  int wm = (wave >> 1) * 64, wn = (wave & 1) * 64;
  int cposR = lq ^ ((l16 >> 2) & 3);
  int ca0 = (2*lq)     ^ (l16 & 7);
  int ca1 = (2*lq + 1) ^ (l16 & 7);
  f32x4 acc[4][4] = {};
  for (int kt = 0; kt < K; kt += 32){
    __syncthreads();
    #pragma unroll
    for (int i = 0; i < 4; i++){
      int u = tid + 256*i;
      int r = u >> 3, cpos = u & 7, cg = cpos ^ (r & 7);
      load_lds_16B(&A[(size_t)(m0 + r) * K + kt + cg*4], (char*)Asf + (wave*64 + 256*i)*16);
    }
    #pragma unroll
    for (int i = 0; i < 2; i++){
      int u = tid + 256*i;
      int r = u >> 2, cpos = u & 3, cg = cpos ^ ((r >> 2) & 3);
      load_lds_16B(&Wcat[(size_t)(n0g + r) * K + kt + cg*8], (char*)Bs + (wave*64 + 256*i)*16);
    }
    __syncthreads();
    bf16x8 af[4], bfr[4];
    #pragma unroll
    for (int t = 0; t < 4; t++){
      int row = wm + t*16 + l16;
      f32x4 x0 = *reinterpret_cast<f32x4*>(&Asf[row*32 + ca0*4]);
      f32x4 x1 = *reinterpret_cast<f32x4*>(&Asf[row*32 + ca1*4]);
      bf16x8 a;
      a[0] = (bf16_t)x0[0]; a[1] = (bf16_t)x0[1]; a[2] = (bf16_t)x0[2]; a[3] = (bf16_t)x0[3];
      a[4] = (bf16_t)x1[0]; a[5] = (bf16_t)x1[1]; a[6] = (bf16_t)x1[2]; a[7] = (bf16_t)x1[3];
      af[t] = a;
    }
    #pragma unroll
    for (int t = 0; t < 4; t++) bfr[t] = *reinterpret_cast<bf16x8*>(&Bs[(wn + t*16 + l16)*32 + cposR*8]);
    #pragma unroll
    for (int ti = 0; ti < 4; ti++)
      #pragma unroll
      for (int tj = 0; tj < 4; tj++)
        acc[ti][tj] = __builtin_amdgcn_mfma_f32_16x16x32_bf16(af[ti], bfr[tj], acc[ti][tj], 0, 0, 0);
  }
  qkv_epilogue(acc, seg, n0g, m0, wm, wn, l16, lq, bias, qp, kp, vh);
}

// ---------------- output GEMM: d_out = ctx @ Wot^T + bo, fp32 out ----------------
__global__ __launch_bounds__(256) void gemm_out(const bf16_t* __restrict__ A,
                                                const bf16_t* __restrict__ Bt,
                                                const float* __restrict__ bias,
                                                float* __restrict__ C){
  const int K = 1024, N = 1024;
  __shared__ __align__(16) bf16_t As[128*64];
  __shared__ __align__(16) bf16_t Bs[64*64];
  int tid = threadIdx.x, wave = tid >> 6, lane = tid & 63;
  int l16 = lane & 15, lq = lane >> 4;
  int m0 = blockIdx.y * 128, n0 = blockIdx.x * 64;
  int wm = wave * 32;
  f32x4 acc[2][4] = {};
  for (int kt = 0; kt < K; kt += 64){
    __syncthreads();
    #pragma unroll
    for (int i = 0; i < 4; i++){
      int u = tid + 256*i;
      int r = u >> 3, cpos = u & 7, cg = cpos ^ (r & 7);
      load_lds_16B(&A[(size_t)(m0 + r) * K + kt + cg*8], (char*)As + (wave*64 + 256*i)*16);
    }
    #pragma unroll
    for (int i = 0; i < 2; i++){
      int u = tid + 256*i;
      int r = u >> 3, cpos = u & 7, cg = cpos ^ (r & 7);
      load_lds_16B(&Bt[(size_t)(n0 + r) * K + kt + cg*8], (char*)Bs + (wave*64 + 256*i)*16);
    }
    __syncthreads();
    #pragma unroll
    for (int kk = 0; kk < 2; kk++){
      bf16x8 af[2], bfr[4];
      #pragma unroll
      for (int t = 0; t < 2; t++){
        int row = wm + t*16 + l16, cpos = (kk*4 + lq) ^ (l16 & 7);
        af[t] = *reinterpret_cast<bf16x8*>(&As[row*64 + cpos*8]);
      }
      #pragma unroll
      for (int t = 0; t < 4; t++){
        int row = t*16 + l16, cpos = (kk*4 + lq) ^ (l16 & 7);
        bfr[t] = *reinterpret_cast<bf16x8*>(&Bs[row*64 + cpos*8]);
      }
      #pragma unroll
      for (int ti = 0; ti < 2; ti++)
        #pragma unroll
        for (int tj = 0; tj < 4; tj++)
          acc[ti][tj] = __builtin_amdgcn_mfma_f32_16x16x32_bf16(af[ti], bfr[tj], acc[ti][tj], 0, 0, 0);
    }
  }
  #pragma unroll
  for (int ti = 0; ti < 2; ti++){
    #pragma unroll
    for (int tj = 0; tj < 4; tj++){
      int col = n0 + tj*16 + l16;
      float bvv = bias[col];
      #pragma unroll
      for (int r = 0; r < 4; r++){
        int row = m0 + wm + ti*16 + lq*4 + r;
        C[(size_t)row * N + col] = acc[ti][tj][r] + bvv;
      }
    }
  }
}

// ---------------- per-head V transpose: vh[b*2048+s][h*64+d] -> Vt[(b*16+h)*64+d][s] ----------------
__global__ __launch_bounds__(256) void vtrans_kernel(const bf16_t* __restrict__ vh,
                                                     bf16_t* __restrict__ Vt){
  __shared__ bf16_t T[64][72];
  int tid = threadIdx.x;
  int s0 = blockIdx.x * 64, h = blockIdx.y, b = blockIdx.z;
  #pragma unroll
  for (int i = 0; i < 2; i++){
    int u = tid + 256*i;
    int r = u >> 3, c = (u & 7) * 8;
    *reinterpret_cast<uint4*>(&T[r][c]) =
      *reinterpret_cast<const uint4*>(&vh[(size_t)(b*2048 + s0 + r) * 1024 + h*64 + c]);
  }
  __syncthreads();
  #pragma unroll
  for (int i = 0; i < 2; i++){
    int u = tid + 256*i;
    int d = u >> 3, cs = (u & 7) * 8;
    bf16_t t8[8];
    #pragma unroll
    for (int j = 0; j < 8; j++) t8[j] = T[cs + j][d];
    *reinterpret_cast<uint4*>(&Vt[(size_t)((b*16 + h)*64 + d) * 2048 + s0 + cs]) =
      *reinterpret_cast<uint4*>(t8);
  }
}

// ---------------- flash attention v7: 128 q-rows/block, 2 q-subtiles per wave (ILP) ------
// Grid (16,16,2) = 512 blocks, 4 waves = (qhalf, khalf), launch_bounds(256,2) -> VGPR<=256.
// Each wave: TWO independent 32-q subtiles (j=0,1) vs its 32 keys of the 64-key tile.
// K-frag, V-frag, mask loads and all staging shared across both subtiles: LDS reads/FLOP
// and K/V HBM re-fetch halve vs v5; independent j-chains give the scheduler MFMA/VALU
// overlap (QK(j=1) MFMAs hide exp/shfl(j=0)). Same verified per-tile structure as round-1:
// mask C-init from prescaled global floats, prefetch-then-drain single __syncthreads per
// tile (2x compute phase now fully covers stage latency), ones-MFMA row-sums (lmm).
// LDS: K dbuf 16K + V dbuf 16K + Lsum[128] = 33.3 KB; epilogue Opart overlays 32 KB.
__global__ __launch_bounds__(256, 2) void attn_kernel(const bf16_t* __restrict__ qp,
                                                      const bf16_t* __restrict__ kp,
                                                      const bf16_t* __restrict__ vt,
                                                      const float* __restrict__ ms,
                                                      bf16_t* __restrict__ ctx){
  const int S = 2048, D = 1024, HD = 64;
  __shared__ __align__(16) char smem[33280];
  // K bufs [0,16384), V bufs [16384,32768), Lsum [32768, +512)
  float* Lsum  = (float*)(smem + 32768);   // [128]
  float* Opart = (float*)smem;             // epilogue overlay: 32 KB
  int tid = threadIdx.x, wave = tid >> 6, lane = tid & 63;
  int l32 = lane & 31, H = lane >> 5;
  int qhalf = wave & 1, khalf = wave >> 1;
  int qt = blockIdx.x, h = blockIdx.y, b = blockIdx.z;
  const bf16_t* Qg = qp + (size_t)b*S*D + h*HD;
  const bf16_t* Kg = kp + (size_t)b*S*D + h*HD;
  const bf16_t* Vg = vt + (size_t)(b*16 + h)*HD*S;
  const float*  Mg = ms + (size_t)b*S;

  auto stage = [&](int kt, int bsel){
    char* Kd = smem + bsel*8192;
    char* Vd = smem + 16384 + bsel*8192;
    #pragma unroll
    for (int i = 0; i < 2; i++){
      int u = tid + 256*i;
      int r = u >> 3, c = u & 7, cg = c ^ (r & 7);
      int ldsoff = (wave*64 + 256*i) * 16;  // wave-uniform base; HW adds lane*16
      load_lds_16B(&Kg[(size_t)(kt + r) * D + cg*8], Kd + ldsoff);
      load_lds_16B(&Vg[(size_t)r * S + kt + cg*8], Vd + ldsoff);
    }
  };

  // Q fragments straight from global: B-operand, lane n=qrow, k=d=16s+8H+j
  // subtile j covers q-rows [qt*128 + j*64 + qhalf*32, +32)
  bf16x8 qf[2][4];
  #pragma unroll
  for (int j = 0; j < 2; j++){
    int qrow = qt*128 + j*64 + qhalf*32 + l32;
    #pragma unroll
    for (int s = 0; s < 4; s++)
      qf[j][s] = *reinterpret_cast<const bf16x8*>(&Qg[(size_t)qrow * D + s*16 + 8*H]);
  }

  f32x16 o0[2], o1[2], lmm[2];
  #pragma unroll
  for (int j = 0; j < 2; j++){ o0[j] = zero16(); o1[j] = zero16(); lmm[j] = zero16(); }
  int krow = khalf*32 + l32;

  pk16 ones;
  ones.h[0].x = 0x3F803F80u; ones.h[0].y = 0x3F803F80u;
  ones.h[1].x = 0x3F803F80u; ones.h[1].y = 0x3F803F80u;

  stage(0, 0);
  __syncthreads();
  int cur = 0;

  for (int kt = 0; kt < S; kt += 64){
    // mask bias loads FIRST (before stage issue) so their wait leaves prefetch in flight
    cinit_t ci;
    #pragma unroll
    for (int g = 0; g < 4; g++)
      ci.f4[g] = *reinterpret_cast<const float4*>(&Mg[kt + khalf*32 + 8*g + 4*H]);

    if (kt + 64 < S) stage(kt + 64, cur ^ 1);

    bf16_t* Ks  = (bf16_t*)(smem + cur*8192);
    bf16_t* Vts = (bf16_t*)(smem + 16384 + cur*8192);

    // K fragments once, shared by both subtiles
    bf16x8 kf[4];
    #pragma unroll
    for (int s = 0; s < 4; s++){
      int cp = (2*s + H) ^ (l32 & 7);  // krow&7 == l32&7
      kf[s] = *reinterpret_cast<bf16x8*>(&Ks[krow*64 + cp*8]);
    }

    // QK + exp per subtile; j=0 and j=1 chains independent -> scheduler overlaps
    pk8 grp[2][4];
    #pragma unroll
    for (int j = 0; j < 2; j++){
      f32x16 sc = __builtin_amdgcn_mfma_f32_32x32x16_bf16(kf[0], qf[j][0], ci.v, 0, 0, 0);
      #pragma unroll
      for (int s = 1; s < 4; s++)
        sc = __builtin_amdgcn_mfma_f32_32x32x16_bf16(kf[s], qf[j][s], sc, 0, 0, 0);
      #pragma unroll
      for (int g = 0; g < 4; g++){
        float p0 = EXP2F(sc[4*g+0]);
        float p1 = EXP2F(sc[4*g+1]);
        float p2 = EXP2F(sc[4*g+2]);
        float p3 = EXP2F(sc[4*g+3]);
        pk8 w;
        w.b4[0] = (bf16_t)p0; w.b4[1] = (bf16_t)p1; w.b4[2] = (bf16_t)p2; w.b4[3] = (bf16_t)p3;
        grp[j][g] = w;
      }
    }

    // PV: V fragments once per kk, shared by both subtiles; ones-MFMA row-sums
    #pragma unroll
    for (int kk = 0; kk < 2; kk++){
      int cp = (4*khalf + 2*kk + H) ^ (l32 & 7);
      bf16x8 vf0 = *reinterpret_cast<bf16x8*>(&Vts[l32*64 + cp*8]);
      bf16x8 vf1 = *reinterpret_cast<bf16x8*>(&Vts[(32 + l32)*64 + cp*8]);
      #pragma unroll
      for (int j = 0; j < 2; j++){
        uint2 ga = grp[j][2*kk].u2;
        uint2 gb = grp[j][2*kk+1].u2;
        uint2 send = H ? ga : gb;
        uint2 recv;
        recv.x = (unsigned)__shfl_xor((int)send.x, 32);
        recv.y = (unsigned)__shfl_xor((int)send.y, 32);
        pk16 fr;
        fr.h[0] = H ? recv : ga;
        fr.h[1] = H ? gb : recv;
        o0[j]  = __builtin_amdgcn_mfma_f32_32x32x16_bf16(fr.b8, vf0, o0[j], 0, 0, 0);
        o1[j]  = __builtin_amdgcn_mfma_f32_32x32x16_bf16(fr.b8, vf1, o1[j], 0, 0, 0);
        lmm[j] = __builtin_amdgcn_mfma_f32_32x32x16_bf16(fr.b8, ones.b8, lmm[j], 0, 0, 0);
      }
    }
    __syncthreads();
    cur ^= 1;
  }

  // epilogue: combine k-halves through LDS (overlays K/V bufs), normalize, store
  if (khalf == 1){
    #pragma unroll
    for (int j = 0; j < 2; j++){
      #pragma unroll
      for (int reg = 0; reg < 16; reg++){
        Opart[(j*2 + qhalf)*2048 + reg*64 + lane]        = o0[j][reg];
        Opart[(j*2 + qhalf)*2048 + 1024 + reg*64 + lane] = o1[j][reg];
      }
      if (l32 == 0){
        #pragma unroll
        for (int reg = 0; reg < 16; reg++)
          Lsum[j*64 + qhalf*32 + (reg & 3) + 8*(reg >> 2) + 4*H] = lmm[j][reg];
      }
    }
  }
  __syncthreads();
  if (khalf == 0){
    #pragma unroll
    for (int j = 0; j < 2; j++){
      #pragma unroll
      for (int reg = 0; reg < 16; reg++){
        o0[j][reg] += Opart[(j*2 + qhalf)*2048 + reg*64 + lane];
        o1[j][reg] += Opart[(j*2 + qhalf)*2048 + 1024 + reg*64 + lane];
      }
      #pragma unroll
      for (int g = 0; g < 4; g++){
        #pragma unroll
        for (int r = 0; r < 4; r++){
          float lf = lmm[j][4*g + r] + Lsum[j*64 + qhalf*32 + 8*g + 4*H + r];
          float inv = 1.f / lf;
          int grow = qt*128 + j*64 + qhalf*32 + 8*g + 4*H + r;
          size_t base = (size_t)(b*S + grow) * D + h*HD;
          ctx[base + l32]      = (bf16_t)(o0[j][4*g + r] * inv);
          ctx[base + 32 + l32] = (bf16_t)(o1[j][4*g + r] * inv);
        }
      }
    }
  }
}

extern "C" void kernel_launch(void* const* d_in, const int* in_sizes, int n_in,
                              void* d_out, int out_size, void* d_ws, size_t ws_size,
                              hipStream_t stream){
  const float* q    = (const float*)d_in[0];
  const float* k    = (const float*)d_in[1];
  const float* v    = (const float*)d_in[2];
  const float* mask = (const float*)d_in[3];
  const float* Wq   = (const float*)d_in[4];
  const float* bq   = (const float*)d_in[5];
  const float* Wk   = (const float*)d_in[6];
  const float* bk   = (const float*)d_in[7];
  const float* Wv   = (const float*)d_in[8];
  const float* bv   = (const float*)d_in[9];
  const float* Wo   = (const float*)d_in[10];
  const float* bo   = (const float*)d_in[11];

  char* ws = (char*)d_ws;
  bf16_t* qp    = (bf16_t*)(ws);               // [0, 8 MiB)
  bf16_t* kp    = (bf16_t*)(ws + 8388608);     // [8, 16)
  bf16_t* vh    = (bf16_t*)(ws + 16777216);    // [16, 24)
  bf16_t* Wcat  = (bf16_t*)(ws + 25165824);    // [24, 30)
  bf16_t* Wot   = (bf16_t*)(ws + 31457280);    // [30, 32)
  bf16_t* Vt    = (bf16_t*)(ws + 33554432);    // [32, 40)
  bf16_t* ctx   = (bf16_t*)(ws + 41943040);    // [40, 48)
  bf16_t* qkvin = (bf16_t*)(ws + 33554432);    // [32, 56) path A only; dead before Vt/ctx live
  float*  msbuf = (float*)(ws + 16777216);     // 16 KB, overlays vh (dead after vtrans)

  wtrans4_kernel<<<dim3(32,32,4), dim3(32,8), 0, stream>>>(Wq, Wk, Wv, Wo, Wcat, Wot);
  if (ws_size >= 58720256){
    cast3_kernel<<<dim3(4096,3), 256, 0, stream>>>(q, k, v, qkvin);
    gemm_qkv_bf<<<dim3(24,32), 256, 0, stream>>>(qkvin, Wcat, bq, bk, bv, qp, kp, vh);
  } else {
    gemm_qkv_f32<<<dim3(24,32), 256, 0, stream>>>(q, k, v, Wcat, bq, bk, bv, qp, kp, vh);
  }
  vtrans_kernel<<<dim3(32,16,2), 256, 0, stream>>>(vh, Vt);
  mask_scale_kernel<<<dim3(16), 256, 0, stream>>>(mask, msbuf);
  attn_kernel<<<dim3(16,16,2), 256, 0, stream>>>(qp, kp, Vt, msbuf, ctx);
  gemm_out<<<dim3(16,32), 256, 0, stream>>>(ctx, Wot, bo, (float*)d_out);
}